// Round 7
// baseline (3961.951 us; speedup 1.0000x reference)
//
#include <hip/hip_runtime.h>
#include <hip/hip_bf16.h>
#include <hip/hip_cooperative_groups.h>

namespace coopg = cooperative_groups;

#define NN 100000
#define NE 3200000
#define IN_F 512
#define NH 64
#define NC 16
#define K_HOPS 10

#define BSPAN 256
#define NBUCKC ((NN + BSPAN - 1) / BSPAN)   // 391
#define NBUCKP 512
#define CAP 9216
#define PART_BLOCKS 256
#define PCHUNK ((NE + PART_BLOCKS - 1) / PART_BLOCKS)  // 12500

#define MH_BLOCKS 1536
#define MH_THREADS (MH_BLOCKS * 256)        // 393216
#define N_ITEMS (NN * 4)                    // 400000

typedef short bf16x8 __attribute__((ext_vector_type(8)));
typedef float f32x4 __attribute__((ext_vector_type(4)));
typedef unsigned short u16;
typedef u16 u16x4 __attribute__((ext_vector_type(4)));

__device__ __forceinline__ short f2bf_s(float x) {
    __hip_bfloat16 b = __float2bfloat16(x);
    return *reinterpret_cast<short*>(&b);
}
__device__ __forceinline__ float bf2f_s(short s) {
    __hip_bfloat16 b = *reinterpret_cast<__hip_bfloat16*>(&s);
    return __bfloat162float(b);
}
__device__ __forceinline__ f32x4 bf4_to_f32(u16x4 v) {
    f32x4 r;
    r[0] = __uint_as_float((unsigned)v[0] << 16);
    r[1] = __uint_as_float((unsigned)v[1] << 16);
    r[2] = __uint_as_float((unsigned)v[2] << 16);
    r[3] = __uint_as_float((unsigned)v[3] << 16);
    return r;
}

__device__ __forceinline__ void split8(const f32x4 a, const f32x4 b,
                                       bf16x8& hi, bf16x8& lo) {
    float x[8] = {a[0], a[1], a[2], a[3], b[0], b[1], b[2], b[3]};
#pragma unroll
    for (int j = 0; j < 8; ++j) {
        short h = f2bf_s(x[j]);
        hi[j] = h;
        lo[j] = f2bf_s(x[j] - bf2f_s(h));
    }
}

__device__ __forceinline__ f32x4 mfma3(bf16x8 ah, bf16x8 al, bf16x8 bh,
                                       bf16x8 bl, f32x4 c) {
    c = __builtin_amdgcn_mfma_f32_16x16x32_bf16(ah, bh, c, 0, 0, 0);
    c = __builtin_amdgcn_mfma_f32_16x16x32_bf16(ah, bl, c, 0, 0, 0);
    c = __builtin_amdgcn_mfma_f32_16x16x32_bf16(al, bh, c, 0, 0, 0);
    return c;
}

// ---------- prep: weights -> hi/lo bf16 (transposed); also init gcur ----------
__global__ __launch_bounds__(256) void conv_w_kernel(
    const float* __restrict__ W1, const float* __restrict__ W2,
    short* __restrict__ w1h, short* __restrict__ w1l,
    short* __restrict__ w2h, short* __restrict__ w2l,
    int* __restrict__ gcur)
{
    int i = blockIdx.x * 256 + threadIdx.x;
    if (i < NBUCKP) gcur[i] = i * CAP;
    if (i < IN_F * NH) {
        int k = i >> 6, n = i & 63;
        float v = W1[i];
        short h = f2bf_s(v);
        w1h[n * IN_F + k] = h;
        w1l[n * IN_F + k] = f2bf_s(v - bf2f_s(h));
    } else if (i < IN_F * NH + NH * NC) {
        int j = i - IN_F * NH;
        int k = j >> 4, c = j & 15;
        float v = W2[j];
        short h = f2bf_s(v);
        w2h[c * NH + k] = h;
        w2l[c * NH + k] = f2bf_s(v - bf2f_s(h));
    }
}

// ---------- encoder: z(bf16) = relu(X@W1+b1)@W2+b2 ; hid = temp[0]*z ----------
__global__ __launch_bounds__(256) void encoder_mfma(
    const float* __restrict__ X,
    const short* __restrict__ w1h, const short* __restrict__ w1l,
    const short* __restrict__ w2h, const short* __restrict__ w2l,
    const float* __restrict__ b1, const float* __restrict__ b2,
    const float* __restrict__ temp,
    u16* __restrict__ z, float* __restrict__ hid)
{
    __shared__ float hs[128 * 68];
    const int t = threadIdx.x;
    const int wave = t >> 6, lane = t & 63;
    const int lm = lane & 15, kg = lane >> 4;
    const int wrow = blockIdx.x * 128 + wave * 32;

    int r0 = wrow + lm;       if (r0 > NN - 1) r0 = NN - 1;
    int r1 = wrow + 16 + lm;  if (r1 > NN - 1) r1 = NN - 1;
    const float* xp0 = X + (size_t)r0 * IN_F + kg * 8;
    const float* xp1 = X + (size_t)r1 * IN_F + kg * 8;
    const short* bhp = w1h + lm * IN_F + kg * 8;
    const short* blp = w1l + lm * IN_F + kg * 8;

    f32x4 acc[2][4];
#pragma unroll
    for (int m = 0; m < 2; ++m)
#pragma unroll
        for (int n = 0; n < 4; ++n) acc[m][n] = (f32x4){0.f, 0.f, 0.f, 0.f};

    for (int kb = 0; kb < IN_F; kb += 32) {
        bf16x8 ah0, al0, ah1, al1;
        {
            const f32x4* p0 = reinterpret_cast<const f32x4*>(xp0 + kb);
            split8(p0[0], p0[1], ah0, al0);
            const f32x4* p1 = reinterpret_cast<const f32x4*>(xp1 + kb);
            split8(p1[0], p1[1], ah1, al1);
        }
#pragma unroll
        for (int nt = 0; nt < 4; ++nt) {
            bf16x8 bh = *reinterpret_cast<const bf16x8*>(bhp + nt * 16 * IN_F + kb);
            bf16x8 bl = *reinterpret_cast<const bf16x8*>(blp + nt * 16 * IN_F + kb);
            acc[0][nt] = mfma3(ah0, al0, bh, bl, acc[0][nt]);
            acc[1][nt] = mfma3(ah1, al1, bh, bl, acc[1][nt]);
        }
    }

    float b1v[4];
#pragma unroll
    for (int nt = 0; nt < 4; ++nt) b1v[nt] = b1[nt * 16 + lm];
#pragma unroll
    for (int m = 0; m < 2; ++m)
#pragma unroll
        for (int nt = 0; nt < 4; ++nt)
#pragma unroll
            for (int r = 0; r < 4; ++r) {
                float v = acc[m][nt][r] + b1v[nt];
                v = v > 0.f ? v : 0.f;
                hs[(wave * 32 + m * 16 + kg * 4 + r) * 68 + nt * 16 + lm] = v;
            }

    f32x4 acc2[2];
    acc2[0] = (f32x4){0.f, 0.f, 0.f, 0.f};
    acc2[1] = (f32x4){0.f, 0.f, 0.f, 0.f};
#pragma unroll
    for (int kb = 0; kb < NH; kb += 32) {
        bf16x8 bh = *reinterpret_cast<const bf16x8*>(w2h + lm * NH + kb + kg * 8);
        bf16x8 bl = *reinterpret_cast<const bf16x8*>(w2l + lm * NH + kb + kg * 8);
#pragma unroll
        for (int m = 0; m < 2; ++m) {
            const f32x4* hp = reinterpret_cast<const f32x4*>(
                &hs[(wave * 32 + m * 16 + lm) * 68 + kb + kg * 8]);
            bf16x8 ah, al;
            split8(hp[0], hp[1], ah, al);
            acc2[m] = mfma3(ah, al, bh, bl, acc2[m]);
        }
    }

    const float b2v = b2[lm];
    const float t0 = temp[0];
#pragma unroll
    for (int m = 0; m < 2; ++m)
#pragma unroll
        for (int r = 0; r < 4; ++r) {
            int node = wrow + m * 16 + kg * 4 + r;
            if (node < NN) {
                float zv = acc2[m][r] + b2v;
                z[(size_t)node * NC + lm] = (u16)f2bf_s(zv);
                hid[(size_t)node * NC + lm] = t0 * zv;
            }
        }
}

// ---------- partition: edges -> fixed-cap bucket regions ----------
__global__ __launch_bounds__(1024) void partition_kernel(
    const int* __restrict__ src, const int* __restrict__ dst,
    const float* __restrict__ w, int* __restrict__ gcur,
    int2* __restrict__ ew)
{
    __shared__ int h[16][NBUCKP];
    __shared__ int base[NBUCKP];
    __shared__ int rnk[NBUCKP];
    const int t = threadIdx.x;
    const int wid = t >> 6;
    for (int i = t; i < 16 * NBUCKP; i += 1024) ((int*)h)[i] = 0;
    __syncthreads();
    const int s = blockIdx.x * PCHUNK;
    int e = s + PCHUNK; if (e > NE) e = NE;
    for (int i = s + t; i < e; i += 1024)
        atomicAdd(&h[wid][dst[i] >> 8], 1);
    __syncthreads();
    for (int b = t; b < NBUCKP; b += 1024) {
        int tot = 0;
#pragma unroll
        for (int ww = 0; ww < 16; ++ww) tot += h[ww][b];
        base[b] = tot ? atomicAdd(&gcur[b], tot) : 0;
        rnk[b] = 0;
    }
    __syncthreads();
    for (int i = s + t; i < e; i += 1024) {
        int d = dst[i];
        int b = d >> 8;
        int r = atomicAdd(&rnk[b], 1);
        unsigned x = (unsigned)src[i] | ((unsigned)(d & 255) << 24);
        ew[base[b] + r] = make_int2((int)x, __float_as_int(w[i]));
    }
}

// ---------- bucketfill: per coarse bucket, node-sort edges, emit rowse ----------
__global__ __launch_bounds__(256) void bucketfill_kernel(
    const int* __restrict__ gcur, long long* __restrict__ ew,
    int2* __restrict__ rowse)
{
    __shared__ long long buf[CAP];
    __shared__ int cnt[BSPAN], excl[BSPAN], rnk[BSPAN];
    const int b = blockIdx.x;
    const int base = b * CAP;
    int n = gcur[b] - base;
    if (n > CAP) n = CAP;
    const int t = threadIdx.x;
    cnt[t] = 0;
    __syncthreads();
    for (int i = t; i < n; i += 256) {
        long long v = ew[base + i];
        buf[i] = v;
        atomicAdd(&cnt[(int)((v >> 24) & 255)], 1);
    }
    __syncthreads();
    int sv = cnt[t];
    excl[t] = sv;
    __syncthreads();
    for (int off = 1; off < 256; off <<= 1) {
        int u = (t >= off) ? excl[t - off] : 0;
        __syncthreads();
        excl[t] += u;
        __syncthreads();
    }
    int myExcl = excl[t] - sv;
    __syncthreads();
    excl[t] = myExcl;
    rnk[t] = 0;
    int node = b * BSPAN + t;
    if (node < NN) rowse[node] = make_int2(base + myExcl, sv);
    __syncthreads();
    for (int i = t; i < n; i += 256) {
        long long v = buf[i];
        int d = (int)((v >> 24) & 255);
        int r = atomicAdd(&rnk[d], 1);
        ew[base + excl[d] + r] = v & 0xFFFFFFFF00FFFFFFll;
    }
}

// ---------- shared row-accumulate helper ----------
__device__ __forceinline__ f32x4 row_accum(
    int e, int e1, int cg_, const long long* __restrict__ ew,
    const u16x4* __restrict__ inv)
{
    f32x4 a0 = (f32x4){0.f, 0.f, 0.f, 0.f};
    f32x4 a1 = a0, a2 = a0, a3 = a0;
    for (; e + 3 < e1; e += 4) {
        long long q0 = __builtin_nontemporal_load(ew + e);
        long long q1 = __builtin_nontemporal_load(ew + e + 1);
        long long q2 = __builtin_nontemporal_load(ew + e + 2);
        long long q3 = __builtin_nontemporal_load(ew + e + 3);
        int s0 = (int)(q0 & 0x00FFFFFFll);
        int s1 = (int)(q1 & 0x00FFFFFFll);
        int s2 = (int)(q2 & 0x00FFFFFFll);
        int s3 = (int)(q3 & 0x00FFFFFFll);
        float w0 = __uint_as_float((unsigned)((unsigned long long)q0 >> 32));
        float w1 = __uint_as_float((unsigned)((unsigned long long)q1 >> 32));
        float w2 = __uint_as_float((unsigned)((unsigned long long)q2 >> 32));
        float w3 = __uint_as_float((unsigned)((unsigned long long)q3 >> 32));
        u16x4 v0 = inv[(size_t)s0 * 4 + cg_];
        u16x4 v1 = inv[(size_t)s1 * 4 + cg_];
        u16x4 v2 = inv[(size_t)s2 * 4 + cg_];
        u16x4 v3 = inv[(size_t)s3 * 4 + cg_];
        a0 += w0 * bf4_to_f32(v0);
        a1 += w1 * bf4_to_f32(v1);
        a2 += w2 * bf4_to_f32(v2);
        a3 += w3 * bf4_to_f32(v3);
    }
    for (; e < e1; ++e) {
        long long q0 = __builtin_nontemporal_load(ew + e);
        int s0 = (int)(q0 & 0x00FFFFFFll);
        float w0 = __uint_as_float((unsigned)((unsigned long long)q0 >> 32));
        a0 += w0 * bf4_to_f32(inv[(size_t)s0 * 4 + cg_]);
    }
    return (a0 + a1) + (a2 + a3);
}

// ---------- cooperative multi-hop: all 10 hops in one launch ----------
// hid accumulates in registers; grid.sync() between hops.
__global__ __launch_bounds__(256, 6) void multihop_kernel(
    const int2* __restrict__ rowse, const long long* __restrict__ ew,
    u16* __restrict__ stA, u16* __restrict__ stB,
    float* __restrict__ hid, const float* __restrict__ temp)
{
    coopg::grid_group grid = coopg::this_grid();
    const int t0 = blockIdx.x * 256 + threadIdx.x;
    const int i1 = t0 + MH_THREADS;
    const bool has2 = (i1 < N_ITEMS);

    const int d0 = t0 >> 2, c0 = t0 & 3;
    const int d1 = i1 >> 2, c1 = i1 & 3;
    const int2 rs0 = rowse[d0];
    const int2 rs1 = has2 ? rowse[d1] : make_int2(0, 0);
    f32x4 hid0 = reinterpret_cast<const f32x4*>(hid)[t0];
    f32x4 hid1 = has2 ? reinterpret_cast<const f32x4*>(hid)[i1]
                      : (f32x4){0.f, 0.f, 0.f, 0.f};

    for (int k = 1; k <= K_HOPS; ++k) {
        if (k > 1) { __threadfence(); grid.sync(); }
        const u16* in  = (k & 1) ? stA : stB;
        u16*       out = (k & 1) ? stB : stA;
        const u16x4* inv = reinterpret_cast<const u16x4*>(in);
        const float tk = temp[k];
        const int last = (k == K_HOPS);

        f32x4 r0 = row_accum(rs0.x, rs0.x + rs0.y, c0, ew, inv);
        hid0 += tk * r0;
        if (!last) {
            u16x4 ro;
            ro[0] = (u16)f2bf_s(r0[0]);
            ro[1] = (u16)f2bf_s(r0[1]);
            ro[2] = (u16)f2bf_s(r0[2]);
            ro[3] = (u16)f2bf_s(r0[3]);
            reinterpret_cast<u16x4*>(out)[t0] = ro;
        }
        if (has2) {
            f32x4 r1 = row_accum(rs1.x, rs1.x + rs1.y, c1, ew, inv);
            hid1 += tk * r1;
            if (!last) {
                u16x4 ro;
                ro[0] = (u16)f2bf_s(r1[0]);
                ro[1] = (u16)f2bf_s(r1[1]);
                ro[2] = (u16)f2bf_s(r1[2]);
                ro[3] = (u16)f2bf_s(r1[3]);
                reinterpret_cast<u16x4*>(out)[i1] = ro;
            }
        }
    }
    reinterpret_cast<f32x4*>(hid)[t0] = hid0;
    if (has2) reinterpret_cast<f32x4*>(hid)[i1] = hid1;
}

// ---------- fallback per-hop kernel (non-cooperative path) ----------
__global__ __launch_bounds__(256) void hop_kernel(
    const int2* __restrict__ rowse, const long long* __restrict__ ew,
    const u16* __restrict__ in, u16* __restrict__ out,
    float* __restrict__ hid, const float* __restrict__ temp, int k, int last)
{
    int tid = blockIdx.x * 256 + threadIdx.x;
    int d = tid >> 2, cg_ = tid & 3;
    if (d >= NN) return;
    int2 rs = rowse[d];
    const u16x4* inv = reinterpret_cast<const u16x4*>(in);
    f32x4 r = row_accum(rs.x, rs.x + rs.y, cg_, ew, inv);
    size_t o = (size_t)d * 4 + cg_;
    if (!last) {
        u16x4 ro;
        ro[0] = (u16)f2bf_s(r[0]);
        ro[1] = (u16)f2bf_s(r[1]);
        ro[2] = (u16)f2bf_s(r[2]);
        ro[3] = (u16)f2bf_s(r[3]);
        reinterpret_cast<u16x4*>(out)[o] = ro;
    }
    const float tk = temp[k];
    reinterpret_cast<f32x4*>(hid)[o] += tk * r;
}

// ---------- fallback (small ws): atomic scatter on bf16 state ----------
__global__ __launch_bounds__(256) void spmm_atomic_bf16(
    const int* __restrict__ src, const int* __restrict__ dst,
    const float* __restrict__ w, const u16* __restrict__ in,
    float* __restrict__ outf)
{
    int tid = blockIdx.x * 256 + threadIdx.x;
    int e = tid >> 4, c = tid & 15;
    if (e >= NE) return;
    float v = __uint_as_float((unsigned)in[(size_t)src[e] * NC + c] << 16);
    atomicAdd(&outf[(size_t)dst[e] * NC + c], w[e] * v);
}
__global__ __launch_bounds__(256) void axpy_quant_kernel(
    float* __restrict__ hid, const float* __restrict__ outf,
    u16* __restrict__ nextb, const float* __restrict__ temp, int k)
{
    int i = blockIdx.x * 256 + threadIdx.x;
    if (i < NN * NC) {
        float r = outf[i];
        hid[i] += temp[k] * r;
        nextb[i] = (u16)f2bf_s(r);
    }
}

extern "C" void kernel_launch(void* const* d_in, const int* in_sizes, int n_in,
                              void* d_out, int out_size, void* d_ws, size_t ws_size,
                              hipStream_t stream)
{
    const float* feature = (const float*)d_in[0];
    const float* W1      = (const float*)d_in[1];
    const float* b1      = (const float*)d_in[2];
    const float* W2      = (const float*)d_in[3];
    const float* b2      = (const float*)d_in[4];
    const int*   edges   = (const int*)d_in[5];
    const float* norm_A  = (const float*)d_in[6];
    const float* temp    = (const float*)d_in[7];
    const int* src = edges;
    const int* dst = edges + NE;
    float* hid = (float*)d_out;

    char* p = (char*)d_ws;
    size_t off = 0;
    auto carve = [&](size_t bytes) {
        void* r = p + off;
        off += (bytes + 255) & ~(size_t)255;
        return r;
    };
    u16*   zkA   = (u16*)carve((size_t)NN * NC * 2);
    u16*   zkB   = (u16*)carve((size_t)NN * NC * 2);
    short* w1h   = (short*)carve((size_t)IN_F * NH * 2);
    short* w1l   = (short*)carve((size_t)IN_F * NH * 2);
    short* w2h   = (short*)carve((size_t)NH * NC * 2);
    short* w2l   = (short*)carve((size_t)NH * NC * 2);
    int*   gcur  = (int*)carve((size_t)NBUCKP * 4);
    int2*  rowse = (int2*)carve((size_t)NN * 8);
    int2*  ew    = (int2*)carve((size_t)NBUCKC * CAP * 8);   // 28.8 MB
    const bool useCSR = (off <= ws_size);

    conv_w_kernel<<<(IN_F * NH + NH * NC + 255) / 256, 256, 0, stream>>>(
        W1, W2, w1h, w1l, w2h, w2l, gcur);
    encoder_mfma<<<(NN + 127) / 128, 256, 0, stream>>>(
        feature, w1h, w1l, w2h, w2l, b1, b2, temp, zkA, hid);

    if (useCSR) {
        partition_kernel<<<PART_BLOCKS, 1024, 0, stream>>>(src, dst, norm_A,
                                                           gcur, ew);
        bucketfill_kernel<<<NBUCKC, 256, 0, stream>>>(gcur, (long long*)ew,
                                                      rowse);

        // cooperative multi-hop; fall back to per-hop dispatches if rejected
        const int2* rowse_c = rowse;
        const long long* ew_c = (const long long*)ew;
        u16* stA = zkA;
        u16* stB = zkB;
        const float* temp_c = temp;
        void* args[6] = {(void*)&rowse_c, (void*)&ew_c, (void*)&stA,
                         (void*)&stB, (void*)&hid, (void*)&temp_c};
        hipError_t err = hipLaunchCooperativeKernel(
            (const void*)multihop_kernel, dim3(MH_BLOCKS), dim3(256),
            args, 0, stream);
        if (err != hipSuccess) {
            const int hopGrid = (NN * 4 + 255) / 256;
            u16* cur = zkA;
            u16* nxt = zkB;
            for (int k = 1; k <= K_HOPS; ++k) {
                hop_kernel<<<hopGrid, 256, 0, stream>>>(
                    rowse, (const long long*)ew, cur, nxt, hid, temp, k,
                    k == K_HOPS);
                u16* t2 = cur; cur = nxt; nxt = t2;
            }
        }
    } else {
        char* q = (char*)d_ws;
        size_t stride = ((size_t)NN * NC * 2 + 255) & ~(size_t)255;
        u16* inA = (u16*)q;
        u16* inB = (u16*)(q + stride);
        float* outf = (float*)(q + 2 * stride + 512 * 1024);
        const int spmmGrid = (NE * NC + 255) / 256;
        const int vecGrid  = (NN * NC + 255) / 256;
        u16* cur = inA; u16* nxt = inB;
        for (int k = 1; k <= K_HOPS; ++k) {
            hipMemsetAsync(outf, 0, (size_t)NN * NC * 4, stream);
            spmm_atomic_bf16<<<spmmGrid, 256, 0, stream>>>(src, dst, norm_A,
                                                           cur, outf);
            axpy_quant_kernel<<<vecGrid, 256, 0, stream>>>(hid, outf, nxt,
                                                           temp, k);
            u16* t2 = cur; cur = nxt; nxt = t2;
        }
    }
}

// Round 8
// 1523.638 us; speedup vs baseline: 2.6003x; 2.6003x over previous
//
#include <hip/hip_runtime.h>
#include <hip/hip_bf16.h>

#define NN 100000
#define NE 3200000
#define IN_F 512
#define NH 64
#define NC 16
#define K_HOPS 10

#define BSPAN 256
#define NBUCKC ((NN + BSPAN - 1) / BSPAN)   // 391
#define NBUCKP 512
#define CAP 9216
#define PART_BLOCKS 256
#define PCHUNK ((NE + PART_BLOCKS - 1) / PART_BLOCKS)  // 12500

#define SLICE (NN * 4)                      // u16 (or f32) per cg-slice row-block
#define HOP_CHUNKS 196                      // 196*512 = 100352 >= NN
#define HOP_BLOCKS (HOP_CHUNKS * 8)         // 1568

typedef short bf16x8 __attribute__((ext_vector_type(8)));
typedef float f32x4 __attribute__((ext_vector_type(4)));
typedef unsigned short u16;
typedef u16 u16x4 __attribute__((ext_vector_type(4)));

__device__ __forceinline__ short f2bf_s(float x) {
    __hip_bfloat16 b = __float2bfloat16(x);
    return *reinterpret_cast<short*>(&b);
}
__device__ __forceinline__ float bf2f_s(short s) {
    __hip_bfloat16 b = *reinterpret_cast<__hip_bfloat16*>(&s);
    return __bfloat162float(b);
}
__device__ __forceinline__ f32x4 bf4_to_f32(u16x4 v) {
    f32x4 r;
    r[0] = __uint_as_float((unsigned)v[0] << 16);
    r[1] = __uint_as_float((unsigned)v[1] << 16);
    r[2] = __uint_as_float((unsigned)v[2] << 16);
    r[3] = __uint_as_float((unsigned)v[3] << 16);
    return r;
}
__device__ __forceinline__ u16x4 f32_to_bf4(f32x4 r) {
    u16x4 o;
    o[0] = (u16)f2bf_s(r[0]);
    o[1] = (u16)f2bf_s(r[1]);
    o[2] = (u16)f2bf_s(r[2]);
    o[3] = (u16)f2bf_s(r[3]);
    return o;
}

__device__ __forceinline__ void split8(const f32x4 a, const f32x4 b,
                                       bf16x8& hi, bf16x8& lo) {
    float x[8] = {a[0], a[1], a[2], a[3], b[0], b[1], b[2], b[3]};
#pragma unroll
    for (int j = 0; j < 8; ++j) {
        short h = f2bf_s(x[j]);
        hi[j] = h;
        lo[j] = f2bf_s(x[j] - bf2f_s(h));
    }
}

__device__ __forceinline__ f32x4 mfma3(bf16x8 ah, bf16x8 al, bf16x8 bh,
                                       bf16x8 bl, f32x4 c) {
    c = __builtin_amdgcn_mfma_f32_16x16x32_bf16(ah, bh, c, 0, 0, 0);
    c = __builtin_amdgcn_mfma_f32_16x16x32_bf16(ah, bl, c, 0, 0, 0);
    c = __builtin_amdgcn_mfma_f32_16x16x32_bf16(al, bh, c, 0, 0, 0);
    return c;
}

// ---------- prep: weights -> hi/lo bf16 (transposed); also init gcur ----------
__global__ __launch_bounds__(256) void conv_w_kernel(
    const float* __restrict__ W1, const float* __restrict__ W2,
    short* __restrict__ w1h, short* __restrict__ w1l,
    short* __restrict__ w2h, short* __restrict__ w2l,
    int* __restrict__ gcur)
{
    int i = blockIdx.x * 256 + threadIdx.x;
    if (i < NBUCKP) gcur[i] = i * CAP;
    if (i < IN_F * NH) {
        int k = i >> 6, n = i & 63;
        float v = W1[i];
        short h = f2bf_s(v);
        w1h[n * IN_F + k] = h;
        w1l[n * IN_F + k] = f2bf_s(v - bf2f_s(h));
    } else if (i < IN_F * NH + NH * NC) {
        int j = i - IN_F * NH;
        int k = j >> 4, c = j & 15;
        float v = W2[j];
        short h = f2bf_s(v);
        w2h[c * NH + k] = h;
        w2l[c * NH + k] = f2bf_s(v - bf2f_s(h));
    }
}

// ---------- encoder: z(bf16, cg-major) = relu(X@W1+b1)@W2+b2 ----------
// also hidw (f32, cg-major) = temp[0]*z
__global__ __launch_bounds__(256) void encoder_mfma(
    const float* __restrict__ X,
    const short* __restrict__ w1h, const short* __restrict__ w1l,
    const short* __restrict__ w2h, const short* __restrict__ w2l,
    const float* __restrict__ b1, const float* __restrict__ b2,
    const float* __restrict__ temp,
    u16* __restrict__ z, float* __restrict__ hidw)
{
    __shared__ float hs[128 * 68];
    const int t = threadIdx.x;
    const int wave = t >> 6, lane = t & 63;
    const int lm = lane & 15, kg = lane >> 4;
    const int wrow = blockIdx.x * 128 + wave * 32;

    int r0 = wrow + lm;       if (r0 > NN - 1) r0 = NN - 1;
    int r1 = wrow + 16 + lm;  if (r1 > NN - 1) r1 = NN - 1;
    const float* xp0 = X + (size_t)r0 * IN_F + kg * 8;
    const float* xp1 = X + (size_t)r1 * IN_F + kg * 8;
    const short* bhp = w1h + lm * IN_F + kg * 8;
    const short* blp = w1l + lm * IN_F + kg * 8;

    f32x4 acc[2][4];
#pragma unroll
    for (int m = 0; m < 2; ++m)
#pragma unroll
        for (int n = 0; n < 4; ++n) acc[m][n] = (f32x4){0.f, 0.f, 0.f, 0.f};

    for (int kb = 0; kb < IN_F; kb += 32) {
        bf16x8 ah0, al0, ah1, al1;
        {
            const f32x4* p0 = reinterpret_cast<const f32x4*>(xp0 + kb);
            split8(p0[0], p0[1], ah0, al0);
            const f32x4* p1 = reinterpret_cast<const f32x4*>(xp1 + kb);
            split8(p1[0], p1[1], ah1, al1);
        }
#pragma unroll
        for (int nt = 0; nt < 4; ++nt) {
            bf16x8 bh = *reinterpret_cast<const bf16x8*>(bhp + nt * 16 * IN_F + kb);
            bf16x8 bl = *reinterpret_cast<const bf16x8*>(blp + nt * 16 * IN_F + kb);
            acc[0][nt] = mfma3(ah0, al0, bh, bl, acc[0][nt]);
            acc[1][nt] = mfma3(ah1, al1, bh, bl, acc[1][nt]);
        }
    }

    float b1v[4];
#pragma unroll
    for (int nt = 0; nt < 4; ++nt) b1v[nt] = b1[nt * 16 + lm];
#pragma unroll
    for (int m = 0; m < 2; ++m)
#pragma unroll
        for (int nt = 0; nt < 4; ++nt)
#pragma unroll
            for (int r = 0; r < 4; ++r) {
                float v = acc[m][nt][r] + b1v[nt];
                v = v > 0.f ? v : 0.f;
                hs[(wave * 32 + m * 16 + kg * 4 + r) * 68 + nt * 16 + lm] = v;
            }

    f32x4 acc2[2];
    acc2[0] = (f32x4){0.f, 0.f, 0.f, 0.f};
    acc2[1] = (f32x4){0.f, 0.f, 0.f, 0.f};
#pragma unroll
    for (int kb = 0; kb < NH; kb += 32) {
        bf16x8 bh = *reinterpret_cast<const bf16x8*>(w2h + lm * NH + kb + kg * 8);
        bf16x8 bl = *reinterpret_cast<const bf16x8*>(w2l + lm * NH + kb + kg * 8);
#pragma unroll
        for (int m = 0; m < 2; ++m) {
            const f32x4* hp = reinterpret_cast<const f32x4*>(
                &hs[(wave * 32 + m * 16 + lm) * 68 + kb + kg * 8]);
            bf16x8 ah, al;
            split8(hp[0], hp[1], ah, al);
            acc2[m] = mfma3(ah, al, bh, bl, acc2[m]);
        }
    }

    const float b2v = b2[lm];
    const float t0 = temp[0];
    const size_t cgOff = (size_t)(lm >> 2) * SLICE;
    const int jj = lm & 3;
#pragma unroll
    for (int m = 0; m < 2; ++m)
#pragma unroll
        for (int r = 0; r < 4; ++r) {
            int node = wrow + m * 16 + kg * 4 + r;
            if (node < NN) {
                float zv = acc2[m][r] + b2v;
                z[cgOff + (size_t)node * 4 + jj] = (u16)f2bf_s(zv);
                hidw[cgOff + (size_t)node * 4 + jj] = t0 * zv;
            }
        }
}

// ---------- partition: edges -> fixed-cap bucket regions ----------
__global__ __launch_bounds__(1024) void partition_kernel(
    const int* __restrict__ src, const int* __restrict__ dst,
    const float* __restrict__ w, int* __restrict__ gcur,
    int2* __restrict__ ew)
{
    __shared__ int h[16][NBUCKP];
    __shared__ int base[NBUCKP];
    __shared__ int rnk[NBUCKP];
    const int t = threadIdx.x;
    const int wid = t >> 6;
    for (int i = t; i < 16 * NBUCKP; i += 1024) ((int*)h)[i] = 0;
    __syncthreads();
    const int s = blockIdx.x * PCHUNK;
    int e = s + PCHUNK; if (e > NE) e = NE;
    for (int i = s + t; i < e; i += 1024)
        atomicAdd(&h[wid][dst[i] >> 8], 1);
    __syncthreads();
    for (int b = t; b < NBUCKP; b += 1024) {
        int tot = 0;
#pragma unroll
        for (int ww = 0; ww < 16; ++ww) tot += h[ww][b];
        base[b] = tot ? atomicAdd(&gcur[b], tot) : 0;
        rnk[b] = 0;
    }
    __syncthreads();
    for (int i = s + t; i < e; i += 1024) {
        int d = dst[i];
        int b = d >> 8;
        int r = atomicAdd(&rnk[b], 1);
        unsigned x = (unsigned)src[i] | ((unsigned)(d & 255) << 24);
        ew[base[b] + r] = make_int2((int)x, __float_as_int(w[i]));
    }
}

// ---------- bucketfill: per coarse bucket, node-sort edges, emit rowse ----------
__global__ __launch_bounds__(256) void bucketfill_kernel(
    const int* __restrict__ gcur, long long* __restrict__ ew,
    int2* __restrict__ rowse)
{
    __shared__ long long buf[CAP];
    __shared__ int cnt[BSPAN], excl[BSPAN], rnk[BSPAN];
    const int b = blockIdx.x;
    const int base = b * CAP;
    int n = gcur[b] - base;
    if (n > CAP) n = CAP;
    const int t = threadIdx.x;
    cnt[t] = 0;
    __syncthreads();
    for (int i = t; i < n; i += 256) {
        long long v = ew[base + i];
        buf[i] = v;
        atomicAdd(&cnt[(int)((v >> 24) & 255)], 1);
    }
    __syncthreads();
    int sv = cnt[t];
    excl[t] = sv;
    __syncthreads();
    for (int off = 1; off < 256; off <<= 1) {
        int u = (t >= off) ? excl[t - off] : 0;
        __syncthreads();
        excl[t] += u;
        __syncthreads();
    }
    int myExcl = excl[t] - sv;
    __syncthreads();
    excl[t] = myExcl;
    rnk[t] = 0;
    int node = b * BSPAN + t;
    if (node < NN) rowse[node] = make_int2(base + myExcl, sv);
    __syncthreads();
    for (int i = t; i < n; i += 256) {
        long long v = buf[i];
        int d = (int)((v >> 24) & 255);
        int r = atomicAdd(&rnk[d], 1);
        ew[base + excl[d] + r] = v & 0xFFFFFFFF00FFFFFFll;
    }
}

// ---------- row accumulate: 8-way unrolled gather-reduce over one CSR row ----------
__device__ __forceinline__ f32x4 row_accum(
    int e, int e1, const long long* __restrict__ ew,
    const u16x4* __restrict__ inv)
{
    f32x4 a0 = (f32x4){0.f, 0.f, 0.f, 0.f};
    f32x4 a1 = a0, a2 = a0, a3 = a0;
    for (; e + 7 < e1; e += 8) {
        long long q0 = __builtin_nontemporal_load(ew + e);
        long long q1 = __builtin_nontemporal_load(ew + e + 1);
        long long q2 = __builtin_nontemporal_load(ew + e + 2);
        long long q3 = __builtin_nontemporal_load(ew + e + 3);
        long long q4 = __builtin_nontemporal_load(ew + e + 4);
        long long q5 = __builtin_nontemporal_load(ew + e + 5);
        long long q6 = __builtin_nontemporal_load(ew + e + 6);
        long long q7 = __builtin_nontemporal_load(ew + e + 7);
        u16x4 v0 = inv[(size_t)(q0 & 0x00FFFFFFll)];
        u16x4 v1 = inv[(size_t)(q1 & 0x00FFFFFFll)];
        u16x4 v2 = inv[(size_t)(q2 & 0x00FFFFFFll)];
        u16x4 v3 = inv[(size_t)(q3 & 0x00FFFFFFll)];
        u16x4 v4 = inv[(size_t)(q4 & 0x00FFFFFFll)];
        u16x4 v5 = inv[(size_t)(q5 & 0x00FFFFFFll)];
        u16x4 v6 = inv[(size_t)(q6 & 0x00FFFFFFll)];
        u16x4 v7 = inv[(size_t)(q7 & 0x00FFFFFFll)];
        a0 += __uint_as_float((unsigned)((unsigned long long)q0 >> 32)) * bf4_to_f32(v0);
        a1 += __uint_as_float((unsigned)((unsigned long long)q1 >> 32)) * bf4_to_f32(v1);
        a2 += __uint_as_float((unsigned)((unsigned long long)q2 >> 32)) * bf4_to_f32(v2);
        a3 += __uint_as_float((unsigned)((unsigned long long)q3 >> 32)) * bf4_to_f32(v3);
        a0 += __uint_as_float((unsigned)((unsigned long long)q4 >> 32)) * bf4_to_f32(v4);
        a1 += __uint_as_float((unsigned)((unsigned long long)q5 >> 32)) * bf4_to_f32(v5);
        a2 += __uint_as_float((unsigned)((unsigned long long)q6 >> 32)) * bf4_to_f32(v6);
        a3 += __uint_as_float((unsigned)((unsigned long long)q7 >> 32)) * bf4_to_f32(v7);
    }
    for (; e + 1 < e1; e += 2) {
        long long q0 = __builtin_nontemporal_load(ew + e);
        long long q1 = __builtin_nontemporal_load(ew + e + 1);
        u16x4 v0 = inv[(size_t)(q0 & 0x00FFFFFFll)];
        u16x4 v1 = inv[(size_t)(q1 & 0x00FFFFFFll)];
        a0 += __uint_as_float((unsigned)((unsigned long long)q0 >> 32)) * bf4_to_f32(v0);
        a1 += __uint_as_float((unsigned)((unsigned long long)q1 >> 32)) * bf4_to_f32(v1);
    }
    if (e < e1) {
        long long q0 = __builtin_nontemporal_load(ew + e);
        a0 += __uint_as_float((unsigned)((unsigned long long)q0 >> 32)) *
              bf4_to_f32(inv[(size_t)(q0 & 0x00FFFFFFll)]);
    }
    return (a0 + a1) + (a2 + a3);
}

// ---------- hop: cg-major state, XCD-affine column slices ----------
// blockIdx: xcd = b&7 -> cg = xcd>>1; 256 consecutive rows per block.
__global__ __launch_bounds__(256) void hop_kernel(
    const int2* __restrict__ rowse, const long long* __restrict__ ew,
    const u16* __restrict__ in, u16* __restrict__ out,
    float* __restrict__ hidw, float* __restrict__ dout,
    const float* __restrict__ temp, int k, int last)
{
    const int b = blockIdx.x;
    const int xcd = b & 7;
    const int cg = xcd >> 1;
    const int d = (b >> 3) * 512 + (xcd & 1) * 256 + threadIdx.x;
    if (d >= NN) return;
    int2 rs = rowse[d];
    const u16x4* inv = reinterpret_cast<const u16x4*>(in + (size_t)cg * SLICE);
    f32x4 r = row_accum(rs.x, rs.x + rs.y, ew, inv);
    const float tk = temp[k];
    float* hw = hidw + (size_t)cg * SLICE;
    if (!last) {
        reinterpret_cast<u16x4*>(out + (size_t)cg * SLICE)[d] = f32_to_bf4(r);
        reinterpret_cast<f32x4*>(hw)[d] += tk * r;
    } else {
        f32x4 h = reinterpret_cast<f32x4*>(hw)[d] + tk * r;
        reinterpret_cast<f32x4*>(dout)[(size_t)d * 4 + cg] = h;
    }
}

// ---------- fallback (small ws): atomic scatter on cg-major bf16 state ----------
__global__ __launch_bounds__(256) void spmm_atomic_bf16(
    const int* __restrict__ src, const int* __restrict__ dst,
    const float* __restrict__ w, const u16* __restrict__ in,
    float* __restrict__ outf)
{
    int tid = blockIdx.x * 256 + threadIdx.x;
    int e = tid >> 4, c = tid & 15;
    if (e >= NE) return;
    float v = __uint_as_float(
        (unsigned)in[(size_t)(c >> 2) * SLICE + (size_t)src[e] * 4 + (c & 3)] << 16);
    atomicAdd(&outf[(size_t)dst[e] * NC + c], w[e] * v);
}
__global__ __launch_bounds__(256) void axpy_quant_kernel(
    float* __restrict__ hidw, const float* __restrict__ outf,
    u16* __restrict__ nextb, const float* __restrict__ temp, int k)
{
    int i = blockIdx.x * 256 + threadIdx.x;
    if (i < NN * NC) {
        int d = i >> 4, c = i & 15;
        float r = outf[i];
        size_t idx = (size_t)(c >> 2) * SLICE + (size_t)d * 4 + (c & 3);
        hidw[idx] += temp[k] * r;
        nextb[idx] = (u16)f2bf_s(r);
    }
}
__global__ __launch_bounds__(256) void transpose_out_kernel(
    const float* __restrict__ hidw, float* __restrict__ dout)
{
    int tid = blockIdx.x * 256 + threadIdx.x;
    int d = tid >> 2, cg = tid & 3;
    if (d >= NN) return;
    f32x4 h = reinterpret_cast<const f32x4*>(hidw + (size_t)cg * SLICE)[d];
    reinterpret_cast<f32x4*>(dout)[(size_t)d * 4 + cg] = h;
}

extern "C" void kernel_launch(void* const* d_in, const int* in_sizes, int n_in,
                              void* d_out, int out_size, void* d_ws, size_t ws_size,
                              hipStream_t stream)
{
    const float* feature = (const float*)d_in[0];
    const float* W1      = (const float*)d_in[1];
    const float* b1      = (const float*)d_in[2];
    const float* W2      = (const float*)d_in[3];
    const float* b2      = (const float*)d_in[4];
    const int*   edges   = (const int*)d_in[5];
    const float* norm_A  = (const float*)d_in[6];
    const float* temp    = (const float*)d_in[7];
    const int* src = edges;
    const int* dst = edges + NE;
    float* dout = (float*)d_out;

    char* p = (char*)d_ws;
    size_t off = 0;
    auto carve = [&](size_t bytes) {
        void* r = p + off;
        off += (bytes + 255) & ~(size_t)255;
        return r;
    };
    u16*   zkA   = (u16*)carve((size_t)NN * NC * 2);
    u16*   zkB   = (u16*)carve((size_t)NN * NC * 2);
    float* hidw  = (float*)carve((size_t)NN * NC * 4);
    short* w1h   = (short*)carve((size_t)IN_F * NH * 2);
    short* w1l   = (short*)carve((size_t)IN_F * NH * 2);
    short* w2h   = (short*)carve((size_t)NH * NC * 2);
    short* w2l   = (short*)carve((size_t)NH * NC * 2);
    int*   gcur  = (int*)carve((size_t)NBUCKP * 4);
    int2*  rowse = (int2*)carve((size_t)NN * 8);
    int2*  ew    = (int2*)carve((size_t)NBUCKC * CAP * 8);   // 28.8 MB
    const bool useCSR = (off <= ws_size);

    conv_w_kernel<<<(IN_F * NH + NH * NC + 255) / 256, 256, 0, stream>>>(
        W1, W2, w1h, w1l, w2h, w2l, gcur);
    encoder_mfma<<<(NN + 127) / 128, 256, 0, stream>>>(
        feature, w1h, w1l, w2h, w2l, b1, b2, temp, zkA, hidw);

    if (useCSR) {
        partition_kernel<<<PART_BLOCKS, 1024, 0, stream>>>(src, dst, norm_A,
                                                           gcur, ew);
        bucketfill_kernel<<<NBUCKC, 256, 0, stream>>>(gcur, (long long*)ew,
                                                      rowse);
        u16* cur = zkA;
        u16* nxt = zkB;
        for (int k = 1; k <= K_HOPS; ++k) {
            hop_kernel<<<HOP_BLOCKS, 256, 0, stream>>>(
                rowse, (const long long*)ew, cur, nxt, hidw, dout, temp, k,
                k == K_HOPS);
            u16* t2 = cur; cur = nxt; nxt = t2;
        }
    } else {
        // fallback: atomic scatter (cg-major state), outf aliases ew space
        float* outf = (float*)ew;
        const int spmmGrid = (NE * NC + 255) / 256;
        const int vecGrid  = (NN * NC + 255) / 256;
        u16* cur = zkA; u16* nxt = zkB;
        for (int k = 1; k <= K_HOPS; ++k) {
            hipMemsetAsync(outf, 0, (size_t)NN * NC * 4, stream);
            spmm_atomic_bf16<<<spmmGrid, 256, 0, stream>>>(src, dst, norm_A,
                                                           cur, outf);
            axpy_quant_kernel<<<vecGrid, 256, 0, stream>>>(hidw, outf, nxt,
                                                           temp, k);
            u16* t2 = cur; cur = nxt; nxt = t2;
        }
        transpose_out_kernel<<<(NN * 4 + 255) / 256, 256, 0, stream>>>(hidw,
                                                                       dout);
    }
}

// Round 9
// 522.175 us; speedup vs baseline: 7.5874x; 2.9179x over previous
//
#include <hip/hip_runtime.h>
#include <hip/hip_bf16.h>

#define NN 100000
#define NE 3200000
#define IN_F 512
#define NH 64
#define NC 16
#define K_HOPS 10

#define BSPAN 256
#define NBUCKC ((NN + BSPAN - 1) / BSPAN)   // 391
#define NBUCKP 512
#define CAP 9216
#define PART_BLOCKS 256
#define PCHUNK ((NE + PART_BLOCKS - 1) / PART_BLOCKS)  // 12500

typedef short bf16x8 __attribute__((ext_vector_type(8)));
typedef float f32x4 __attribute__((ext_vector_type(4)));
typedef unsigned short u16;
typedef u16 u16x4 __attribute__((ext_vector_type(4)));

__device__ __forceinline__ short f2bf_s(float x) {
    __hip_bfloat16 b = __float2bfloat16(x);
    return *reinterpret_cast<short*>(&b);
}
__device__ __forceinline__ float bf2f_s(short s) {
    __hip_bfloat16 b = *reinterpret_cast<__hip_bfloat16*>(&s);
    return __bfloat162float(b);
}
__device__ __forceinline__ float bf2f_u(u16 s) {
    return __uint_as_float((unsigned)s << 16);
}
__device__ __forceinline__ f32x4 bf4_to_f32(u16x4 v) {
    f32x4 r;
    r[0] = __uint_as_float((unsigned)v[0] << 16);
    r[1] = __uint_as_float((unsigned)v[1] << 16);
    r[2] = __uint_as_float((unsigned)v[2] << 16);
    r[3] = __uint_as_float((unsigned)v[3] << 16);
    return r;
}
__device__ __forceinline__ u16x4 f32_to_bf4(f32x4 r) {
    u16x4 o;
    o[0] = (u16)f2bf_s(r[0]);
    o[1] = (u16)f2bf_s(r[1]);
    o[2] = (u16)f2bf_s(r[2]);
    o[3] = (u16)f2bf_s(r[3]);
    return o;
}

__device__ __forceinline__ void split8(const f32x4 a, const f32x4 b,
                                       bf16x8& hi, bf16x8& lo) {
    float x[8] = {a[0], a[1], a[2], a[3], b[0], b[1], b[2], b[3]};
#pragma unroll
    for (int j = 0; j < 8; ++j) {
        short h = f2bf_s(x[j]);
        hi[j] = h;
        lo[j] = f2bf_s(x[j] - bf2f_s(h));
    }
}

__device__ __forceinline__ f32x4 mfma3(bf16x8 ah, bf16x8 al, bf16x8 bh,
                                       bf16x8 bl, f32x4 c) {
    c = __builtin_amdgcn_mfma_f32_16x16x32_bf16(ah, bh, c, 0, 0, 0);
    c = __builtin_amdgcn_mfma_f32_16x16x32_bf16(ah, bl, c, 0, 0, 0);
    c = __builtin_amdgcn_mfma_f32_16x16x32_bf16(al, bh, c, 0, 0, 0);
    return c;
}

// ---------- prep: weights -> hi/lo bf16 (transposed); also init gcur ----------
__global__ __launch_bounds__(256) void conv_w_kernel(
    const float* __restrict__ W1, const float* __restrict__ W2,
    short* __restrict__ w1h, short* __restrict__ w1l,
    short* __restrict__ w2h, short* __restrict__ w2l,
    int* __restrict__ gcur)
{
    int i = blockIdx.x * 256 + threadIdx.x;
    if (i < NBUCKP) gcur[i] = i * CAP;
    if (i < IN_F * NH) {
        int k = i >> 6, n = i & 63;
        float v = W1[i];
        short h = f2bf_s(v);
        w1h[n * IN_F + k] = h;
        w1l[n * IN_F + k] = f2bf_s(v - bf2f_s(h));
    } else if (i < IN_F * NH + NH * NC) {
        int j = i - IN_F * NH;
        int k = j >> 4, c = j & 15;
        float v = W2[j];
        short h = f2bf_s(v);
        w2h[c * NH + k] = h;
        w2l[c * NH + k] = f2bf_s(v - bf2f_s(h));
    }
}

// ---------- encoder: z(bf16 row-major) = relu(X@W1+b1)@W2+b2 ; hid = temp[0]*z ----------
__global__ __launch_bounds__(256) void encoder_mfma(
    const float* __restrict__ X,
    const short* __restrict__ w1h, const short* __restrict__ w1l,
    const short* __restrict__ w2h, const short* __restrict__ w2l,
    const float* __restrict__ b1, const float* __restrict__ b2,
    const float* __restrict__ temp,
    u16* __restrict__ z, float* __restrict__ hid)
{
    __shared__ float hs[128 * 68];
    const int t = threadIdx.x;
    const int wave = t >> 6, lane = t & 63;
    const int lm = lane & 15, kg = lane >> 4;
    const int wrow = blockIdx.x * 128 + wave * 32;

    int r0 = wrow + lm;       if (r0 > NN - 1) r0 = NN - 1;
    int r1 = wrow + 16 + lm;  if (r1 > NN - 1) r1 = NN - 1;
    const float* xp0 = X + (size_t)r0 * IN_F + kg * 8;
    const float* xp1 = X + (size_t)r1 * IN_F + kg * 8;
    const short* bhp = w1h + lm * IN_F + kg * 8;
    const short* blp = w1l + lm * IN_F + kg * 8;

    f32x4 acc[2][4];
#pragma unroll
    for (int m = 0; m < 2; ++m)
#pragma unroll
        for (int n = 0; n < 4; ++n) acc[m][n] = (f32x4){0.f, 0.f, 0.f, 0.f};

    for (int kb = 0; kb < IN_F; kb += 32) {
        bf16x8 ah0, al0, ah1, al1;
        {
            const f32x4* p0 = reinterpret_cast<const f32x4*>(xp0 + kb);
            split8(p0[0], p0[1], ah0, al0);
            const f32x4* p1 = reinterpret_cast<const f32x4*>(xp1 + kb);
            split8(p1[0], p1[1], ah1, al1);
        }
#pragma unroll
        for (int nt = 0; nt < 4; ++nt) {
            bf16x8 bh = *reinterpret_cast<const bf16x8*>(bhp + nt * 16 * IN_F + kb);
            bf16x8 bl = *reinterpret_cast<const bf16x8*>(blp + nt * 16 * IN_F + kb);
            acc[0][nt] = mfma3(ah0, al0, bh, bl, acc[0][nt]);
            acc[1][nt] = mfma3(ah1, al1, bh, bl, acc[1][nt]);
        }
    }

    float b1v[4];
#pragma unroll
    for (int nt = 0; nt < 4; ++nt) b1v[nt] = b1[nt * 16 + lm];
#pragma unroll
    for (int m = 0; m < 2; ++m)
#pragma unroll
        for (int nt = 0; nt < 4; ++nt)
#pragma unroll
            for (int r = 0; r < 4; ++r) {
                float v = acc[m][nt][r] + b1v[nt];
                v = v > 0.f ? v : 0.f;
                hs[(wave * 32 + m * 16 + kg * 4 + r) * 68 + nt * 16 + lm] = v;
            }

    f32x4 acc2[2];
    acc2[0] = (f32x4){0.f, 0.f, 0.f, 0.f};
    acc2[1] = (f32x4){0.f, 0.f, 0.f, 0.f};
#pragma unroll
    for (int kb = 0; kb < NH; kb += 32) {
        bf16x8 bh = *reinterpret_cast<const bf16x8*>(w2h + lm * NH + kb + kg * 8);
        bf16x8 bl = *reinterpret_cast<const bf16x8*>(w2l + lm * NH + kb + kg * 8);
#pragma unroll
        for (int m = 0; m < 2; ++m) {
            const f32x4* hp = reinterpret_cast<const f32x4*>(
                &hs[(wave * 32 + m * 16 + lm) * 68 + kb + kg * 8]);
            bf16x8 ah, al;
            split8(hp[0], hp[1], ah, al);
            acc2[m] = mfma3(ah, al, bh, bl, acc2[m]);
        }
    }

    const float b2v = b2[lm];
    const float t0 = temp[0];
#pragma unroll
    for (int m = 0; m < 2; ++m)
#pragma unroll
        for (int r = 0; r < 4; ++r) {
            int node = wrow + m * 16 + kg * 4 + r;
            if (node < NN) {
                float zv = acc2[m][r] + b2v;
                z[(size_t)node * NC + lm] = (u16)f2bf_s(zv);
                hid[(size_t)node * NC + lm] = t0 * zv;
            }
        }
}

// ---------- partition: edges -> fixed-cap bucket regions ----------
__global__ __launch_bounds__(1024) void partition_kernel(
    const int* __restrict__ src, const int* __restrict__ dst,
    const float* __restrict__ w, int* __restrict__ gcur,
    int2* __restrict__ ew)
{
    __shared__ int h[16][NBUCKP];
    __shared__ int base[NBUCKP];
    __shared__ int rnk[NBUCKP];
    const int t = threadIdx.x;
    const int wid = t >> 6;
    for (int i = t; i < 16 * NBUCKP; i += 1024) ((int*)h)[i] = 0;
    __syncthreads();
    const int s = blockIdx.x * PCHUNK;
    int e = s + PCHUNK; if (e > NE) e = NE;
    for (int i = s + t; i < e; i += 1024)
        atomicAdd(&h[wid][dst[i] >> 8], 1);
    __syncthreads();
    for (int b = t; b < NBUCKP; b += 1024) {
        int tot = 0;
#pragma unroll
        for (int ww = 0; ww < 16; ++ww) tot += h[ww][b];
        base[b] = tot ? atomicAdd(&gcur[b], tot) : 0;
        rnk[b] = 0;
    }
    __syncthreads();
    for (int i = s + t; i < e; i += 1024) {
        int d = dst[i];
        int b = d >> 8;
        int r = atomicAdd(&rnk[b], 1);
        unsigned x = (unsigned)src[i] | ((unsigned)(d & 255) << 24);
        ew[base[b] + r] = make_int2((int)x, __float_as_int(w[i]));
    }
}

// ---------- bucketfill: node-sort edges within bucket; emit split srcs/wbf ----------
__global__ __launch_bounds__(256) void bucketfill_kernel(
    const int* __restrict__ gcur, const long long* __restrict__ ew,
    int* __restrict__ srcs, u16* __restrict__ wbf,
    int2* __restrict__ rowse)
{
    __shared__ long long buf[CAP];
    __shared__ int cnt[BSPAN], excl[BSPAN], rnk[BSPAN];
    const int b = blockIdx.x;
    const int base = b * CAP;
    int n = gcur[b] - base;
    if (n > CAP) n = CAP;
    const int t = threadIdx.x;
    cnt[t] = 0;
    __syncthreads();
    for (int i = t; i < n; i += 256) {
        long long v = ew[base + i];
        buf[i] = v;
        atomicAdd(&cnt[(int)((v >> 24) & 255)], 1);
    }
    __syncthreads();
    int sv = cnt[t];
    excl[t] = sv;
    __syncthreads();
    for (int off = 1; off < 256; off <<= 1) {
        int u = (t >= off) ? excl[t - off] : 0;
        __syncthreads();
        excl[t] += u;
        __syncthreads();
    }
    int myExcl = excl[t] - sv;
    __syncthreads();
    excl[t] = myExcl;
    rnk[t] = 0;
    int node = b * BSPAN + t;
    if (node < NN) rowse[node] = make_int2(base + myExcl, sv);
    __syncthreads();
    for (int i = t; i < n; i += 256) {
        long long v = buf[i];
        int d = (int)((v >> 24) & 255);
        int r = atomicAdd(&rnk[d], 1);
        int pos = base + excl[d] + r;
        srcs[pos] = (int)(v & 0x00FFFFFFll);
        wbf[pos] = (u16)f2bf_s(__int_as_float((int)((unsigned long long)v >> 32)));
    }
}

// ---------- hop: 4 lanes/row; vectorized stream loads; gathers coalesce 32B ----------
__global__ __launch_bounds__(256) void hop_kernel(
    const int2* __restrict__ rowse, const int* __restrict__ srcs,
    const u16* __restrict__ wbf, const u16* __restrict__ in,
    u16* __restrict__ out, float* __restrict__ hid,
    const float* __restrict__ temp, int k, int last)
{
    int tid = blockIdx.x * 256 + threadIdx.x;
    int d = tid >> 2, cg = tid & 3;
    if (d >= NN) return;
    int2 rs = rowse[d];
    int e = rs.x;
    const int e1 = rs.x + rs.y;
    const u16x4* inv = reinterpret_cast<const u16x4*>(in);
    f32x4 a0 = (f32x4){0.f, 0.f, 0.f, 0.f};
    f32x4 a1 = a0, a2 = a0, a3 = a0;

    // head: align e to 4
    for (; e < e1 && (e & 3); ++e) {
        float w = bf2f_u(wbf[e]);
        a0 += w * bf4_to_f32(inv[(size_t)srcs[e] * 4 + cg]);
    }
    // body: 8 edges per iteration (two int4 + two u16x4 stream loads)
    for (; e + 7 < e1; e += 8) {
        int4 s4a = *reinterpret_cast<const int4*>(srcs + e);
        int4 s4b = *reinterpret_cast<const int4*>(srcs + e + 4);
        u16x4 w4a = *reinterpret_cast<const u16x4*>(wbf + e);
        u16x4 w4b = *reinterpret_cast<const u16x4*>(wbf + e + 4);
        u16x4 v0 = inv[(size_t)s4a.x * 4 + cg];
        u16x4 v1 = inv[(size_t)s4a.y * 4 + cg];
        u16x4 v2 = inv[(size_t)s4a.z * 4 + cg];
        u16x4 v3 = inv[(size_t)s4a.w * 4 + cg];
        u16x4 v4 = inv[(size_t)s4b.x * 4 + cg];
        u16x4 v5 = inv[(size_t)s4b.y * 4 + cg];
        u16x4 v6 = inv[(size_t)s4b.z * 4 + cg];
        u16x4 v7 = inv[(size_t)s4b.w * 4 + cg];
        a0 += bf2f_u(w4a[0]) * bf4_to_f32(v0);
        a1 += bf2f_u(w4a[1]) * bf4_to_f32(v1);
        a2 += bf2f_u(w4a[2]) * bf4_to_f32(v2);
        a3 += bf2f_u(w4a[3]) * bf4_to_f32(v3);
        a0 += bf2f_u(w4b[0]) * bf4_to_f32(v4);
        a1 += bf2f_u(w4b[1]) * bf4_to_f32(v5);
        a2 += bf2f_u(w4b[2]) * bf4_to_f32(v6);
        a3 += bf2f_u(w4b[3]) * bf4_to_f32(v7);
    }
    // mid: 4 edges
    if (e + 3 < e1) {
        int4 s4a = *reinterpret_cast<const int4*>(srcs + e);
        u16x4 w4a = *reinterpret_cast<const u16x4*>(wbf + e);
        u16x4 v0 = inv[(size_t)s4a.x * 4 + cg];
        u16x4 v1 = inv[(size_t)s4a.y * 4 + cg];
        u16x4 v2 = inv[(size_t)s4a.z * 4 + cg];
        u16x4 v3 = inv[(size_t)s4a.w * 4 + cg];
        a0 += bf2f_u(w4a[0]) * bf4_to_f32(v0);
        a1 += bf2f_u(w4a[1]) * bf4_to_f32(v1);
        a2 += bf2f_u(w4a[2]) * bf4_to_f32(v2);
        a3 += bf2f_u(w4a[3]) * bf4_to_f32(v3);
        e += 4;
    }
    // tail
    for (; e < e1; ++e) {
        float w = bf2f_u(wbf[e]);
        a0 += w * bf4_to_f32(inv[(size_t)srcs[e] * 4 + cg]);
    }

    f32x4 r = (a0 + a1) + (a2 + a3);
    size_t o = (size_t)d * 4 + cg;
    if (!last) reinterpret_cast<u16x4*>(out)[o] = f32_to_bf4(r);
    const float tk = temp[k];
    reinterpret_cast<f32x4*>(hid)[o] += tk * r;
}

// ---------- fallback (small ws): atomic scatter on row-major bf16 state ----------
__global__ __launch_bounds__(256) void spmm_atomic_bf16(
    const int* __restrict__ src, const int* __restrict__ dst,
    const float* __restrict__ w, const u16* __restrict__ in,
    float* __restrict__ outf)
{
    int tid = blockIdx.x * 256 + threadIdx.x;
    int e = tid >> 4, c = tid & 15;
    if (e >= NE) return;
    float v = bf2f_u(in[(size_t)src[e] * NC + c]);
    atomicAdd(&outf[(size_t)dst[e] * NC + c], w[e] * v);
}
__global__ __launch_bounds__(256) void axpy_quant_kernel(
    float* __restrict__ hid, const float* __restrict__ outf,
    u16* __restrict__ nextb, const float* __restrict__ temp, int k)
{
    int i = blockIdx.x * 256 + threadIdx.x;
    if (i < NN * NC) {
        float r = outf[i];
        hid[i] += temp[k] * r;
        nextb[i] = (u16)f2bf_s(r);
    }
}

extern "C" void kernel_launch(void* const* d_in, const int* in_sizes, int n_in,
                              void* d_out, int out_size, void* d_ws, size_t ws_size,
                              hipStream_t stream)
{
    const float* feature = (const float*)d_in[0];
    const float* W1      = (const float*)d_in[1];
    const float* b1      = (const float*)d_in[2];
    const float* W2      = (const float*)d_in[3];
    const float* b2      = (const float*)d_in[4];
    const int*   edges   = (const int*)d_in[5];
    const float* norm_A  = (const float*)d_in[6];
    const float* temp    = (const float*)d_in[7];
    const int* src = edges;
    const int* dst = edges + NE;
    float* hid = (float*)d_out;

    char* p = (char*)d_ws;
    size_t off = 0;
    auto carve = [&](size_t bytes) {
        void* r = p + off;
        off += (bytes + 255) & ~(size_t)255;
        return r;
    };
    u16*   zkA   = (u16*)carve((size_t)NN * NC * 2);
    u16*   zkB   = (u16*)carve((size_t)NN * NC * 2);
    short* w1h   = (short*)carve((size_t)IN_F * NH * 2);
    short* w1l   = (short*)carve((size_t)IN_F * NH * 2);
    short* w2h   = (short*)carve((size_t)NH * NC * 2);
    short* w2l   = (short*)carve((size_t)NH * NC * 2);
    int*   gcur  = (int*)carve((size_t)NBUCKP * 4);
    int2*  rowse = (int2*)carve((size_t)NN * 8);
    int2*  ew    = (int2*)carve((size_t)NBUCKC * CAP * 8);   // 28.8 MB staging
    int*   srcs  = (int*)carve((size_t)NBUCKC * CAP * 4);    // 14.4 MB
    u16*   wbf   = (u16*)carve((size_t)NBUCKC * CAP * 2);    // 7.2 MB
    const bool useCSR = (off <= ws_size);

    conv_w_kernel<<<(IN_F * NH + NH * NC + 255) / 256, 256, 0, stream>>>(
        W1, W2, w1h, w1l, w2h, w2l, gcur);
    encoder_mfma<<<(NN + 127) / 128, 256, 0, stream>>>(
        feature, w1h, w1l, w2h, w2l, b1, b2, temp, zkA, hid);

    if (useCSR) {
        partition_kernel<<<PART_BLOCKS, 1024, 0, stream>>>(src, dst, norm_A,
                                                           gcur, ew);
        bucketfill_kernel<<<NBUCKC, 256, 0, stream>>>(
            gcur, (const long long*)ew, srcs, wbf, rowse);

        const int hopGrid = (NN * 4 + 255) / 256;    // 1563
        u16* cur = zkA;
        u16* nxt = zkB;
        for (int k = 1; k <= K_HOPS; ++k) {
            hop_kernel<<<hopGrid, 256, 0, stream>>>(
                rowse, srcs, wbf, cur, nxt, hid, temp, k, k == K_HOPS);
            u16* t2 = cur; cur = nxt; nxt = t2;
        }
    } else {
        float* outf = (float*)ew;
        const int spmmGrid = (NE * NC + 255) / 256;
        const int vecGrid  = (NN * NC + 255) / 256;
        u16* cur = zkA; u16* nxt = zkB;
        for (int k = 1; k <= K_HOPS; ++k) {
            hipMemsetAsync(outf, 0, (size_t)NN * NC * 4, stream);
            spmm_atomic_bf16<<<spmmGrid, 256, 0, stream>>>(src, dst, norm_A,
                                                           cur, outf);
            axpy_quant_kernel<<<vecGrid, 256, 0, stream>>>(hid, outf, nxt,
                                                           temp, k);
            u16* t2 = cur; cur = nxt; nxt = t2;
        }
    }
}